// Round 1
// baseline (1277.927 us; speedup 1.0000x reference)
//
#include <hip/hip_runtime.h>
#include <math.h>

#define N_NODES 50000
#define N_EDGES 800000
#define D_IN 256
#define D_HID 256
#define D_OUT 128

// ---------------- degree / norm ----------------

__global__ void k_deg_init(float* __restrict__ deg, int n) {
    int i = blockIdx.x * 256 + threadIdx.x;
    if (i < n) deg[i] = 1.0f;  // self-loop
}

__global__ void k_deg_edges(const int* __restrict__ dst, float* __restrict__ deg, int e) {
    int i = blockIdx.x * 256 + threadIdx.x;
    if (i < e) atomicAdd(&deg[dst[i]], 1.0f);
}

__global__ void k_rsqrt(float* __restrict__ deg, int n) {
    int i = blockIdx.x * 256 + threadIdx.x;
    if (i < n) deg[i] = rsqrtf(deg[i]);  // deg >= 1 always (self-loop)
}

// ---------------- GEMM: C[M,N] = op(A)[M,K] * B[K,N] ----------------
// 64x64 tile, 256 threads, 4x4 per thread, K-tile 16.
// RELU_BIAS: A-load becomes relu(A[row][k] + bias[k]) (bias over K dim).

template <bool RELU_BIAS>
__global__ __launch_bounds__(256) void k_gemm(const float* __restrict__ A,
                                              const float* __restrict__ B,
                                              const float* __restrict__ bias,
                                              float* __restrict__ C,
                                              int M, int K, int N) {
    __shared__ float As[64][17];
    __shared__ float Bs[16][68];

    const int t  = threadIdx.x;
    const int tx = t & 15;        // output col group
    const int ty = t >> 4;        // output row group
    const int m0 = blockIdx.x * 64;
    const int n0 = blockIdx.y * 64;

    const int arow = t >> 2;          // 0..63
    const int acol = (t & 3) * 4;     // 0,4,8,12
    const int brow = t >> 4;          // 0..15
    const int bcol = (t & 15) * 4;    // 0..60

    float acc[4][4] = {};

    for (int kt = 0; kt < K; kt += 16) {
        // --- load A tile (64x16) ---
        float4 av = make_float4(0.f, 0.f, 0.f, 0.f);
        const int grow = m0 + arow;
        if (grow < M) {
            av = *(const float4*)(A + (size_t)grow * K + kt + acol);
            if (RELU_BIAS) {
                av.x = fmaxf(av.x + bias[kt + acol + 0], 0.f);
                av.y = fmaxf(av.y + bias[kt + acol + 1], 0.f);
                av.z = fmaxf(av.z + bias[kt + acol + 2], 0.f);
                av.w = fmaxf(av.w + bias[kt + acol + 3], 0.f);
            }
        }
        As[arow][acol + 0] = av.x;
        As[arow][acol + 1] = av.y;
        As[arow][acol + 2] = av.z;
        As[arow][acol + 3] = av.w;

        // --- load B tile (16x64) ---
        float4 bv = *(const float4*)(B + (size_t)(kt + brow) * N + n0 + bcol);
        Bs[brow][bcol + 0] = bv.x;
        Bs[brow][bcol + 1] = bv.y;
        Bs[brow][bcol + 2] = bv.z;
        Bs[brow][bcol + 3] = bv.w;

        __syncthreads();

#pragma unroll
        for (int kk = 0; kk < 16; ++kk) {
            float a0 = As[ty * 4 + 0][kk];
            float a1 = As[ty * 4 + 1][kk];
            float a2 = As[ty * 4 + 2][kk];
            float a3 = As[ty * 4 + 3][kk];
            float b0 = Bs[kk][tx * 4 + 0];
            float b1v = Bs[kk][tx * 4 + 1];
            float b2v = Bs[kk][tx * 4 + 2];
            float b3 = Bs[kk][tx * 4 + 3];
            acc[0][0] += a0 * b0;  acc[0][1] += a0 * b1v;  acc[0][2] += a0 * b2v;  acc[0][3] += a0 * b3;
            acc[1][0] += a1 * b0;  acc[1][1] += a1 * b1v;  acc[1][2] += a1 * b2v;  acc[1][3] += a1 * b3;
            acc[2][0] += a2 * b0;  acc[2][1] += a2 * b1v;  acc[2][2] += a2 * b2v;  acc[2][3] += a2 * b3;
            acc[3][0] += a3 * b0;  acc[3][1] += a3 * b1v;  acc[3][2] += a3 * b2v;  acc[3][3] += a3 * b3;
        }
        __syncthreads();
    }

#pragma unroll
    for (int i = 0; i < 4; ++i) {
        const int row = m0 + ty * 4 + i;
        if (row < M) {
#pragma unroll
            for (int j = 0; j < 4; ++j)
                C[(size_t)row * N + n0 + tx * 4 + j] = acc[i][j];
        }
    }
}

// ---------------- scatter (normalized adjacency) ----------------

// self-loop init: out[i][d] = h[i][d] * dinv[i]^2  (fully overwrites out)
template <int DIM>
__global__ void k_selfloop(const float* __restrict__ h, const float* __restrict__ dinv,
                           float* __restrict__ out, int n) {
    int i = blockIdx.x * 256 + threadIdx.x;
    int node = i / DIM;
    if (node < n) {
        float s = dinv[node];
        out[i] = h[i] * s * s;
    }
}

// per-edge: out[dst][d] += h[src][d] * dinv[src]*dinv[dst]
template <int DIM>
__global__ void k_scatter(const float* __restrict__ h, const float* __restrict__ dinv,
                          const int* __restrict__ src, const int* __restrict__ dst,
                          float* __restrict__ out, int e) {
    int tid = blockIdx.x * 256 + threadIdx.x;
    int edge = tid / DIM;
    int d = tid % DIM;
    if (edge < e) {
        int s = src[edge];
        int tnode = dst[edge];
        float nrm = dinv[s] * dinv[tnode];
        atomicAdd(&out[(size_t)tnode * DIM + d], h[(size_t)s * DIM + d] * nrm);
    }
}

// ---------------- epilogue ----------------

__global__ void k_bias_sigmoid(float* __restrict__ out, const float* __restrict__ b, int total) {
    int i = blockIdx.x * 256 + threadIdx.x;
    if (i < total) {
        float v = out[i] + b[i % D_OUT];
        out[i] = 1.0f / (1.0f + expf(-v));
    }
}

// ---------------- launch ----------------

extern "C" void kernel_launch(void* const* d_in, const int* in_sizes, int n_in,
                              void* d_out, int out_size, void* d_ws, size_t ws_size,
                              hipStream_t stream) {
    const float* x  = (const float*)d_in[0];
    const int*   ei = (const int*)d_in[1];
    const float* W1 = (const float*)d_in[2];
    const float* b1 = (const float*)d_in[3];
    const float* W2 = (const float*)d_in[4];
    const float* b2 = (const float*)d_in[5];
    float* out = (float*)d_out;

    float* ws   = (float*)d_ws;
    float* dinv = ws;                                   // [N]
    float* h1   = ws + 50048;                           // [N,256]
    float* agg1 = h1 + (size_t)N_NODES * D_HID;         // [N,256]
    float* h2   = h1;                                   // reuse h1 region: [N,128]

    const int* src = ei;            // edge_index[0]
    const int* dst = ei + N_EDGES;  // edge_index[1]

    const int blocksN = (N_NODES + 255) / 256;
    const int blocksE = (N_EDGES + 255) / 256;

    // degree + rsqrt
    k_deg_init<<<blocksN, 256, 0, stream>>>(dinv, N_NODES);
    k_deg_edges<<<blocksE, 256, 0, stream>>>(dst, dinv, N_EDGES);
    k_rsqrt<<<blocksN, 256, 0, stream>>>(dinv, N_NODES);

    // layer 1: h1 = x @ W1
    dim3 g1((N_NODES + 63) / 64, D_HID / 64);
    k_gemm<false><<<g1, 256, 0, stream>>>(x, W1, nullptr, h1, N_NODES, D_IN, D_HID);

    // aggregate at 256 dims into agg1
    k_selfloop<D_HID><<<(N_NODES * D_HID + 255) / 256, 256, 0, stream>>>(h1, dinv, agg1, N_NODES);
    k_scatter<D_HID><<<(N_EDGES * D_HID) / 256, 256, 0, stream>>>(h1, dinv, src, dst, agg1, N_EDGES);

    // layer 2: h2 = relu(agg1 + b1) @ W2   (GEMM first => scatter at 128 dims)
    dim3 g2((N_NODES + 63) / 64, D_OUT / 64);
    k_gemm<true><<<g2, 256, 0, stream>>>(agg1, W2, b1, h2, N_NODES, D_HID, D_OUT);

    // aggregate at 128 dims directly into d_out
    k_selfloop<D_OUT><<<(N_NODES * D_OUT + 255) / 256, 256, 0, stream>>>(h2, dinv, out, N_NODES);
    k_scatter<D_OUT><<<(N_EDGES * D_OUT) / 256, 256, 0, stream>>>(h2, dinv, src, dst, out, N_EDGES);

    // bias + sigmoid in place
    k_bias_sigmoid<<<(N_NODES * D_OUT + 255) / 256, 256, 0, stream>>>(out, b2, N_NODES * D_OUT);
}

// Round 2
// 473.006 us; speedup vs baseline: 2.7017x; 2.7017x over previous
//
#include <hip/hip_runtime.h>
#include <math.h>

#define N_NODES 50000
#define N_EDGES 800000
#define D_IN 256
#define D_HID 256
#define D_OUT 128

// ================= degree / dinv =================

__global__ void k_count(const int* __restrict__ dst, int* __restrict__ degI, int e) {
    int i = blockIdx.x * 256 + threadIdx.x;
    if (i < e) atomicAdd(&degI[dst[i]], 1);
}

__global__ void k_dinv(const int* __restrict__ degI, float* __restrict__ dinv, int n) {
    int i = blockIdx.x * 256 + threadIdx.x;
    if (i < n) dinv[i] = rsqrtf((float)(1 + degI[i]));  // +1 self-loop
}

// ================= 3-kernel exclusive scan (50000 ints) =================

__global__ void k_block_sums(const int* __restrict__ degI, int* __restrict__ bsum, int n) {
    __shared__ int s[256];
    int i = blockIdx.x * 256 + threadIdx.x;
    s[threadIdx.x] = (i < n) ? degI[i] : 0;
    __syncthreads();
    for (int st = 128; st > 0; st >>= 1) {
        if (threadIdx.x < st) s[threadIdx.x] += s[threadIdx.x + st];
        __syncthreads();
    }
    if (threadIdx.x == 0) bsum[blockIdx.x] = s[0];
}

__global__ void k_scan_bsums(int* __restrict__ bsum, int nb) {  // single block of 256
    __shared__ int s[256];
    int t = threadIdx.x;
    s[t] = (t < nb) ? bsum[t] : 0;
    __syncthreads();
    for (int off = 1; off < 256; off <<= 1) {
        int v = 0;
        if (t >= off) v = s[t - off];
        __syncthreads();
        if (t >= off) s[t] += v;
        __syncthreads();
    }
    if (t < nb) bsum[t] = (t == 0) ? 0 : s[t - 1];  // exclusive
}

__global__ void k_scan_apply(const int* __restrict__ degI, const int* __restrict__ bsum,
                             int* __restrict__ offs, int* __restrict__ cursor, int n) {
    __shared__ int s[256];
    int t = threadIdx.x;
    int i = blockIdx.x * 256 + t;
    int v = (i < n) ? degI[i] : 0;
    s[t] = v;
    __syncthreads();
    for (int off = 1; off < 256; off <<= 1) {
        int u = 0;
        if (t >= off) u = s[t - off];
        __syncthreads();
        if (t >= off) s[t] += u;
        __syncthreads();
    }
    int excl = s[t] - v + bsum[blockIdx.x];
    if (i < n) {
        offs[i] = excl;
        cursor[i] = excl;
        if (i == n - 1) offs[n] = excl + v;  // total = N_EDGES
    }
}

// ================= bucket fill (CSR by dst) =================

__global__ void k_fill(const int* __restrict__ src, const int* __restrict__ dst,
                       int* __restrict__ cursor, int* __restrict__ ebuf, int e) {
    int i = blockIdx.x * 256 + threadIdx.x;
    if (i < e) {
        int d = dst[i];
        int pos = atomicAdd(&cursor[d], 1);
        ebuf[pos] = src[i];
    }
}

// ================= GEMM: C[M,N] = op(A)[M,K] * B[K,N] =================
// 64x64 tile, 256 threads, 4x4 per thread, K-tile 16.

template <bool RELU_BIAS>
__global__ __launch_bounds__(256) void k_gemm(const float* __restrict__ A,
                                              const float* __restrict__ B,
                                              const float* __restrict__ bias,
                                              float* __restrict__ C,
                                              int M, int K, int N) {
    __shared__ float As[64][17];
    __shared__ float Bs[16][68];

    const int t  = threadIdx.x;
    const int tx = t & 15;
    const int ty = t >> 4;
    const int m0 = blockIdx.x * 64;
    const int n0 = blockIdx.y * 64;

    const int arow = t >> 2;
    const int acol = (t & 3) * 4;
    const int brow = t >> 4;
    const int bcol = (t & 15) * 4;

    float acc[4][4] = {};

    for (int kt = 0; kt < K; kt += 16) {
        float4 av = make_float4(0.f, 0.f, 0.f, 0.f);
        const int grow = m0 + arow;
        if (grow < M) {
            av = *(const float4*)(A + (size_t)grow * K + kt + acol);
            if (RELU_BIAS) {
                av.x = fmaxf(av.x + bias[kt + acol + 0], 0.f);
                av.y = fmaxf(av.y + bias[kt + acol + 1], 0.f);
                av.z = fmaxf(av.z + bias[kt + acol + 2], 0.f);
                av.w = fmaxf(av.w + bias[kt + acol + 3], 0.f);
            }
        }
        As[arow][acol + 0] = av.x;
        As[arow][acol + 1] = av.y;
        As[arow][acol + 2] = av.z;
        As[arow][acol + 3] = av.w;

        float4 bv = *(const float4*)(B + (size_t)(kt + brow) * N + n0 + bcol);
        Bs[brow][bcol + 0] = bv.x;
        Bs[brow][bcol + 1] = bv.y;
        Bs[brow][bcol + 2] = bv.z;
        Bs[brow][bcol + 3] = bv.w;

        __syncthreads();

#pragma unroll
        for (int kk = 0; kk < 16; ++kk) {
            float a0 = As[ty * 4 + 0][kk];
            float a1 = As[ty * 4 + 1][kk];
            float a2 = As[ty * 4 + 2][kk];
            float a3 = As[ty * 4 + 3][kk];
            float b0 = Bs[kk][tx * 4 + 0];
            float b1v = Bs[kk][tx * 4 + 1];
            float b2v = Bs[kk][tx * 4 + 2];
            float b3 = Bs[kk][tx * 4 + 3];
            acc[0][0] += a0 * b0;  acc[0][1] += a0 * b1v;  acc[0][2] += a0 * b2v;  acc[0][3] += a0 * b3;
            acc[1][0] += a1 * b0;  acc[1][1] += a1 * b1v;  acc[1][2] += a1 * b2v;  acc[1][3] += a1 * b3;
            acc[2][0] += a2 * b0;  acc[2][1] += a2 * b1v;  acc[2][2] += a2 * b2v;  acc[2][3] += a2 * b3;
            acc[3][0] += a3 * b0;  acc[3][1] += a3 * b1v;  acc[3][2] += a3 * b2v;  acc[3][3] += a3 * b3;
        }
        __syncthreads();
    }

#pragma unroll
    for (int i = 0; i < 4; ++i) {
        const int row = m0 + ty * 4 + i;
        if (row < M) {
#pragma unroll
            for (int j = 0; j < 4; ++j)
                C[(size_t)row * N + n0 + tx * 4 + j] = acc[i][j];
        }
    }
}

// ================= CSR gather aggregation =================
// One wave per node. VEC = DIM/64 floats per lane.
// out[node] = dinv[node]^2 * h[node] + sum_e dinv[src]*dinv[node]*h[src]
// FINAL: out = sigmoid(acc + bias)

template <int DIM, bool FINAL>
__global__ __launch_bounds__(256) void k_gather(const float* __restrict__ h,
                                                const float* __restrict__ dinv,
                                                const int* __restrict__ offs,
                                                const int* __restrict__ ebuf,
                                                const float* __restrict__ bias,
                                                float* __restrict__ out, int n) {
    constexpr int VEC = DIM / 64;
    const int gw = (blockIdx.x * 256 + threadIdx.x) >> 6;  // global wave id = node
    const int lane = threadIdx.x & 63;
    if (gw >= n) return;

    const int node = gw;
    const float di = dinv[node];
    const int base = lane * VEC;

    float acc[VEC];
    {
        const float selfs = di * di;
        const float* hr = h + (size_t)node * DIM + base;
#pragma unroll
        for (int j = 0; j < VEC; ++j) acc[j] = hr[j] * selfs;
    }

    const int e0 = offs[node];
    const int e1 = offs[node + 1];
    int e = e0;
    for (; e + 1 < e1; e += 2) {
        const int s0 = ebuf[e];
        const int s1 = ebuf[e + 1];
        const float n0 = dinv[s0] * di;
        const float n1 = dinv[s1] * di;
        const float* h0 = h + (size_t)s0 * DIM + base;
        const float* h1p = h + (size_t)s1 * DIM + base;
#pragma unroll
        for (int j = 0; j < VEC; ++j) acc[j] += h0[j] * n0 + h1p[j] * n1;
    }
    if (e < e1) {
        const int s0 = ebuf[e];
        const float n0 = dinv[s0] * di;
        const float* h0 = h + (size_t)s0 * DIM + base;
#pragma unroll
        for (int j = 0; j < VEC; ++j) acc[j] += h0[j] * n0;
    }

    float* op = out + (size_t)node * DIM + base;
    if (FINAL) {
#pragma unroll
        for (int j = 0; j < VEC; ++j) {
            const float v = acc[j] + bias[base + j];
            op[j] = 1.0f / (1.0f + expf(-v));
        }
    } else {
#pragma unroll
        for (int j = 0; j < VEC; ++j) op[j] = acc[j];
    }
}

// ================= launch =================

extern "C" void kernel_launch(void* const* d_in, const int* in_sizes, int n_in,
                              void* d_out, int out_size, void* d_ws, size_t ws_size,
                              hipStream_t stream) {
    const float* x  = (const float*)d_in[0];
    const int*   ei = (const int*)d_in[1];
    const float* W1 = (const float*)d_in[2];
    const float* b1 = (const float*)d_in[3];
    const float* W2 = (const float*)d_in[4];
    const float* b2 = (const float*)d_in[5];
    float* out = (float*)d_out;

    // workspace layout (element counts padded to keep 16B alignment)
    float* wsf   = (float*)d_ws;
    float* dinv  = wsf;                         // [50048]
    int*   degI  = (int*)(wsf + 50048);         // [50048]
    int*   offs  = degI + 50048;                // [50064] (uses 50001)
    int*   cursor= offs + 50064;                // [50048]
    int*   bsum  = cursor + 50048;              // [256]
    int*   ebuf  = bsum + 256;                  // [800000]
    float* h1    = (float*)(ebuf + 800000);     // [50000*256]
    float* agg1  = h1 + (size_t)N_NODES * D_HID;// [50000*256]
    float* h2    = h1;                          // reuse (h1 dead after agg1)

    const int* src = ei;
    const int* dst = ei + N_EDGES;

    const int blocksN = (N_NODES + 255) / 256;  // 196
    const int blocksE = (N_EDGES + 255) / 256;

    // ---- CSR build ----
    hipMemsetAsync(degI, 0, N_NODES * sizeof(int), stream);
    k_count<<<blocksE, 256, 0, stream>>>(dst, degI, N_EDGES);
    k_dinv<<<blocksN, 256, 0, stream>>>(degI, dinv, N_NODES);
    k_block_sums<<<blocksN, 256, 0, stream>>>(degI, bsum, N_NODES);
    k_scan_bsums<<<1, 256, 0, stream>>>(bsum, blocksN);
    k_scan_apply<<<blocksN, 256, 0, stream>>>(degI, bsum, offs, cursor, N_NODES);
    k_fill<<<blocksE, 256, 0, stream>>>(src, dst, cursor, ebuf, N_EDGES);

    // ---- layer 1: h1 = x @ W1 ----
    dim3 g1((N_NODES + 63) / 64, D_HID / 64);
    k_gemm<false><<<g1, 256, 0, stream>>>(x, W1, nullptr, h1, N_NODES, D_IN, D_HID);

    // ---- aggregate (256-dim) into agg1 ----
    {
        const int waves = N_NODES;              // 1 wave per node
        const int blocks = (waves + 3) / 4;     // 4 waves per block
        k_gather<D_HID, false><<<blocks, 256, 0, stream>>>(h1, dinv, offs, ebuf, nullptr, agg1, N_NODES);
    }

    // ---- layer 2: h2 = relu(agg1 + b1) @ W2 ----
    dim3 g2((N_NODES + 63) / 64, D_OUT / 64);
    k_gemm<true><<<g2, 256, 0, stream>>>(agg1, W2, b1, h2, N_NODES, D_HID, D_OUT);

    // ---- aggregate (128-dim) + bias + sigmoid into d_out ----
    {
        const int waves = N_NODES;
        const int blocks = (waves + 3) / 4;
        k_gather<D_OUT, true><<<blocks, 256, 0, stream>>>(h2, dinv, offs, ebuf, b2, out, N_NODES);
    }
}

// Round 3
// 296.970 us; speedup vs baseline: 4.3032x; 1.5928x over previous
//
#include <hip/hip_runtime.h>
#include <hip/hip_bf16.h>
#include <math.h>

#define N_NODES 50000
#define N_EDGES 800000
#define D_IN 256
#define D_HID 256
#define D_OUT 128

typedef unsigned short ushort_t;
typedef __attribute__((ext_vector_type(8))) short bf16x8;
typedef __attribute__((ext_vector_type(4))) float f32x4;

__device__ inline float bf2f(ushort_t u) {
    union { unsigned int i; float f; } v; v.i = ((unsigned int)u) << 16; return v.f;
}
__device__ inline ushort_t f2bf(float f) {
    __hip_bfloat16 h = __float2bfloat16(f);  // RNE
    return *reinterpret_cast<ushort_t*>(&h);
}

// ================= degree / dinv =================

__global__ void k_count(const int* __restrict__ dst, int* __restrict__ degI, int e) {
    int i = blockIdx.x * 256 + threadIdx.x;
    if (i < e) atomicAdd(&degI[dst[i]], 1);
}

__global__ void k_dinv(const int* __restrict__ degI, float* __restrict__ dinv, int n) {
    int i = blockIdx.x * 256 + threadIdx.x;
    if (i < n) dinv[i] = rsqrtf((float)(1 + degI[i]));
}

// ================= 3-kernel exclusive scan =================

__global__ void k_block_sums(const int* __restrict__ degI, int* __restrict__ bsum, int n) {
    __shared__ int s[256];
    int i = blockIdx.x * 256 + threadIdx.x;
    s[threadIdx.x] = (i < n) ? degI[i] : 0;
    __syncthreads();
    for (int st = 128; st > 0; st >>= 1) {
        if (threadIdx.x < st) s[threadIdx.x] += s[threadIdx.x + st];
        __syncthreads();
    }
    if (threadIdx.x == 0) bsum[blockIdx.x] = s[0];
}

__global__ void k_scan_bsums(int* __restrict__ bsum, int nb) {
    __shared__ int s[256];
    int t = threadIdx.x;
    s[t] = (t < nb) ? bsum[t] : 0;
    __syncthreads();
    for (int off = 1; off < 256; off <<= 1) {
        int v = 0;
        if (t >= off) v = s[t - off];
        __syncthreads();
        if (t >= off) s[t] += v;
        __syncthreads();
    }
    if (t < nb) bsum[t] = (t == 0) ? 0 : s[t - 1];
}

__global__ void k_scan_apply(const int* __restrict__ degI, const int* __restrict__ bsum,
                             int* __restrict__ offs, int* __restrict__ cursor, int n) {
    __shared__ int s[256];
    int t = threadIdx.x;
    int i = blockIdx.x * 256 + t;
    int v = (i < n) ? degI[i] : 0;
    s[t] = v;
    __syncthreads();
    for (int off = 1; off < 256; off <<= 1) {
        int u = 0;
        if (t >= off) u = s[t - off];
        __syncthreads();
        if (t >= off) s[t] += u;
        __syncthreads();
    }
    int excl = s[t] - v + bsum[blockIdx.x];
    if (i < n) {
        offs[i] = excl;
        cursor[i] = excl;
        if (i == n - 1) offs[n] = excl + v;
    }
}

__global__ void k_fill(const int* __restrict__ src, const int* __restrict__ dst,
                       int* __restrict__ cursor, int* __restrict__ ebuf, int e) {
    int i = blockIdx.x * 256 + threadIdx.x;
    if (i < e) {
        int d = dst[i];
        int pos = atomicAdd(&cursor[d], 1);
        ebuf[pos] = src[i];
    }
}

// ================= weight transpose+convert: Wt[n][k] = bf16(W[k][n]) =================

__global__ void k_convWT(const float* __restrict__ W, ushort_t* __restrict__ Wt, int K, int N) {
    int i = blockIdx.x * 256 + threadIdx.x;
    if (i < K * N) {
        int k = i / N, n = i % N;
        Wt[(size_t)n * K + k] = f2bf(W[i]);
    }
}

// ================= bf16 MFMA GEMM =================
// C[M,N](bf16) = A[M,K] * Bt[N,K]^T ; 128x128 tile, 4 waves, BK=32.
// A_IS_BF16=false: A fp32, converted to bf16 during LDS staging.

template <bool A_IS_BF16>
__global__ __launch_bounds__(256) void k_gemm_mfma(const void* __restrict__ Av,
                                                   const ushort_t* __restrict__ Bt,
                                                   ushort_t* __restrict__ C,
                                                   int M, int K, int N) {
    __shared__ ushort_t As[128 * 40];  // rows x (32 + 8 pad)
    __shared__ ushort_t Bs[128 * 40];  // cols x (32 + 8 pad)

    const int t = threadIdx.x;
    const int lane = t & 63;
    const int w = t >> 6;
    const int wr = w >> 1, wc = w & 1;
    const int m0 = blockIdx.x * 128;
    const int n0 = blockIdx.y * 128;

    const int srow = t >> 1;         // 0..127
    const int scol = (t & 1) * 16;   // 0 / 16

    f32x4 acc[4][4];
#pragma unroll
    for (int m = 0; m < 4; ++m)
#pragma unroll
        for (int n = 0; n < 4; ++n)
#pragma unroll
            for (int i = 0; i < 4; ++i) acc[m][n][i] = 0.0f;

    for (int kt = 0; kt < K; kt += 32) {
        // ---- stage A (128x32) ----
        const int gr = m0 + srow;
        if (A_IS_BF16) {
            const ushort_t* A = (const ushort_t*)Av;
            uint4 v0 = make_uint4(0, 0, 0, 0), v1 = make_uint4(0, 0, 0, 0);
            if (gr < M) {
                const uint4* p = (const uint4*)(A + (size_t)gr * K + kt + scol);
                v0 = p[0]; v1 = p[1];
            }
            *(uint4*)&As[srow * 40 + scol] = v0;
            *(uint4*)&As[srow * 40 + scol + 8] = v1;
        } else {
            const float* A = (const float*)Av;
#pragma unroll
            for (int i = 0; i < 4; ++i) {
                float4 v = make_float4(0.f, 0.f, 0.f, 0.f);
                if (gr < M) v = *(const float4*)(A + (size_t)gr * K + kt + scol + 4 * i);
                ushort4 u;
                u.x = f2bf(v.x); u.y = f2bf(v.y); u.z = f2bf(v.z); u.w = f2bf(v.w);
                *(ushort4*)&As[srow * 40 + scol + 4 * i] = u;
            }
        }
        // ---- stage B (128 cols x 32) from Bt[N][K] ----
        {
            const uint4* p = (const uint4*)(Bt + (size_t)(n0 + srow) * K + kt + scol);
            uint4 v0 = p[0], v1 = p[1];
            *(uint4*)&Bs[srow * 40 + scol] = v0;
            *(uint4*)&Bs[srow * 40 + scol + 8] = v1;
        }
        __syncthreads();

        const int kg = (lane >> 4) * 8;
        const int lr = lane & 15;
        bf16x8 a[4], b[4];
#pragma unroll
        for (int m = 0; m < 4; ++m)
            a[m] = *(const bf16x8*)&As[(wr * 64 + m * 16 + lr) * 40 + kg];
#pragma unroll
        for (int n = 0; n < 4; ++n)
            b[n] = *(const bf16x8*)&Bs[(wc * 64 + n * 16 + lr) * 40 + kg];
#pragma unroll
        for (int m = 0; m < 4; ++m)
#pragma unroll
            for (int n = 0; n < 4; ++n)
                acc[m][n] = __builtin_amdgcn_mfma_f32_16x16x32_bf16(a[m], b[n], acc[m][n], 0, 0, 0);
        __syncthreads();
    }

    // ---- epilogue: C/D layout col=lane&15, row=(lane>>4)*4+i ----
    const int lr = lane & 15;
    const int rg = (lane >> 4) * 4;
#pragma unroll
    for (int m = 0; m < 4; ++m) {
        const int rb = m0 + wr * 64 + m * 16 + rg;
#pragma unroll
        for (int n = 0; n < 4; ++n) {
            const int col = n0 + wc * 64 + n * 16 + lr;
#pragma unroll
            for (int i = 0; i < 4; ++i) {
                const int row = rb + i;
                if (row < M) C[(size_t)row * N + col] = f2bf(acc[m][n][i]);
            }
        }
    }
}

// ================= bf16 CSR gather =================
// MODE 0: out = bf16(relu(acc + bias))   (layer-1 aggregate -> GEMM2 A operand)
// MODE 1: out = f32(sigmoid(acc + bias)) (final output)

template <int DIM, int MODE>
__global__ __launch_bounds__(256) void k_gather_bf(const ushort_t* __restrict__ h,
                                                   const float* __restrict__ dinv,
                                                   const int* __restrict__ offs,
                                                   const int* __restrict__ ebuf,
                                                   const float* __restrict__ bias,
                                                   void* __restrict__ outv, int n) {
    constexpr int VEC = DIM / 64;  // 4 (DIM=256) or 2 (DIM=128)
    const int node = (blockIdx.x * 256 + threadIdx.x) >> 6;
    const int lane = threadIdx.x & 63;
    if (node >= n) return;

    const float di = dinv[node];
    const int base = lane * VEC;

    float acc[VEC];
    {
        const float s2 = di * di;
        if (VEC == 4) {
            ushort4 u = *(const ushort4*)(h + (size_t)node * DIM + base);
            acc[0] = bf2f(u.x) * s2; acc[1] = bf2f(u.y) * s2;
            acc[2] = bf2f(u.z) * s2; acc[3] = bf2f(u.w) * s2;
        } else {
            ushort2 u = *(const ushort2*)(h + (size_t)node * DIM + base);
            acc[0] = bf2f(u.x) * s2; acc[1] = bf2f(u.y) * s2;
        }
    }

    int e = offs[node];
    const int e1 = offs[node + 1];
    for (; e + 1 < e1; e += 2) {
        const int s0 = ebuf[e];
        const int s1 = ebuf[e + 1];
        const float w0 = dinv[s0] * di;
        const float w1 = dinv[s1] * di;
        if (VEC == 4) {
            ushort4 u0 = *(const ushort4*)(h + (size_t)s0 * DIM + base);
            ushort4 u1 = *(const ushort4*)(h + (size_t)s1 * DIM + base);
            acc[0] += bf2f(u0.x) * w0 + bf2f(u1.x) * w1;
            acc[1] += bf2f(u0.y) * w0 + bf2f(u1.y) * w1;
            acc[2] += bf2f(u0.z) * w0 + bf2f(u1.z) * w1;
            acc[3] += bf2f(u0.w) * w0 + bf2f(u1.w) * w1;
        } else {
            ushort2 u0 = *(const ushort2*)(h + (size_t)s0 * DIM + base);
            ushort2 u1 = *(const ushort2*)(h + (size_t)s1 * DIM + base);
            acc[0] += bf2f(u0.x) * w0 + bf2f(u1.x) * w1;
            acc[1] += bf2f(u0.y) * w0 + bf2f(u1.y) * w1;
        }
    }
    if (e < e1) {
        const int s0 = ebuf[e];
        const float w0 = dinv[s0] * di;
        if (VEC == 4) {
            ushort4 u0 = *(const ushort4*)(h + (size_t)s0 * DIM + base);
            acc[0] += bf2f(u0.x) * w0; acc[1] += bf2f(u0.y) * w0;
            acc[2] += bf2f(u0.z) * w0; acc[3] += bf2f(u0.w) * w0;
        } else {
            ushort2 u0 = *(const ushort2*)(h + (size_t)s0 * DIM + base);
            acc[0] += bf2f(u0.x) * w0; acc[1] += bf2f(u0.y) * w0;
        }
    }

    if (MODE == 0) {
        ushort_t* out = (ushort_t*)outv;
        if (VEC == 4) {
            ushort4 u;
            u.x = f2bf(fmaxf(acc[0] + bias[base + 0], 0.f));
            u.y = f2bf(fmaxf(acc[1] + bias[base + 1], 0.f));
            u.z = f2bf(fmaxf(acc[2] + bias[base + 2], 0.f));
            u.w = f2bf(fmaxf(acc[3] + bias[base + 3], 0.f));
            *(ushort4*)(out + (size_t)node * DIM + base) = u;
        } else {
            ushort2 u;
            u.x = f2bf(fmaxf(acc[0] + bias[base + 0], 0.f));
            u.y = f2bf(fmaxf(acc[1] + bias[base + 1], 0.f));
            *(ushort2*)(out + (size_t)node * DIM + base) = u;
        }
    } else {
        float* out = (float*)outv;
#pragma unroll
        for (int j = 0; j < VEC; ++j) {
            const float v = acc[j] + bias[base + j];
            out[(size_t)node * DIM + base + j] = 1.0f / (1.0f + expf(-v));
        }
    }
}

// ================= launch =================

extern "C" void kernel_launch(void* const* d_in, const int* in_sizes, int n_in,
                              void* d_out, int out_size, void* d_ws, size_t ws_size,
                              hipStream_t stream) {
    const float* x  = (const float*)d_in[0];
    const int*   ei = (const int*)d_in[1];
    const float* W1 = (const float*)d_in[2];
    const float* b1 = (const float*)d_in[3];
    const float* W2 = (const float*)d_in[4];
    const float* b2 = (const float*)d_in[5];
    float* out = (float*)d_out;

    float* wsf    = (float*)d_ws;
    float* dinv   = wsf;                          // [50048] f32
    int*   degI   = (int*)(wsf + 50048);          // [50048]
    int*   offs   = degI + 50048;                 // [50064] (uses 50001)
    int*   cursor = offs + 50064;                 // [50048]
    int*   bsum   = cursor + 50048;               // [256]
    int*   ebuf   = bsum + 256;                   // [800000]
    ushort_t* Wt1 = (ushort_t*)(ebuf + 800000);   // [256*256] bf16
    ushort_t* Wt2 = Wt1 + 256 * 256;              // [128*256] bf16
    ushort_t* h1  = Wt2 + 128 * 256;              // [50000*256] bf16
    ushort_t* agg1= h1 + (size_t)N_NODES * D_HID; // [50000*256] bf16
    ushort_t* h2  = h1;                           // reuse (h1 dead after agg)

    const int* src = ei;
    const int* dst = ei + N_EDGES;

    const int blocksN = (N_NODES + 255) / 256;
    const int blocksE = (N_EDGES + 255) / 256;

    // ---- CSR build + norms ----
    hipMemsetAsync(degI, 0, N_NODES * sizeof(int), stream);
    k_count<<<blocksE, 256, 0, stream>>>(dst, degI, N_EDGES);
    k_dinv<<<blocksN, 256, 0, stream>>>(degI, dinv, N_NODES);
    k_block_sums<<<blocksN, 256, 0, stream>>>(degI, bsum, N_NODES);
    k_scan_bsums<<<1, 256, 0, stream>>>(bsum, blocksN);
    k_scan_apply<<<blocksN, 256, 0, stream>>>(degI, bsum, offs, cursor, N_NODES);
    k_fill<<<blocksE, 256, 0, stream>>>(src, dst, cursor, ebuf, N_EDGES);

    // ---- weight conversion ----
    k_convWT<<<(D_IN * D_HID + 255) / 256, 256, 0, stream>>>(W1, Wt1, D_IN, D_HID);
    k_convWT<<<(D_HID * D_OUT + 255) / 256, 256, 0, stream>>>(W2, Wt2, D_HID, D_OUT);

    // ---- layer 1 GEMM: h1 = bf16(x @ W1) ----
    {
        dim3 g((N_NODES + 127) / 128, D_HID / 128);
        k_gemm_mfma<false><<<g, 256, 0, stream>>>(x, Wt1, h1, N_NODES, D_IN, D_HID);
    }

    // ---- aggregate 256-dim + b1 + relu -> agg1 (bf16) ----
    k_gather_bf<D_HID, 0><<<(N_NODES * 64 + 255) / 256, 256, 0, stream>>>(
        h1, dinv, offs, ebuf, b1, agg1, N_NODES);

    // ---- layer 2 GEMM: h2 = bf16(agg1 @ W2) ----
    {
        dim3 g((N_NODES + 127) / 128, D_OUT / 128);
        k_gemm_mfma<true><<<g, 256, 0, stream>>>(agg1, Wt2, h2, N_NODES, D_HID, D_OUT);
    }

    // ---- aggregate 128-dim + b2 + sigmoid -> out (f32) ----
    k_gather_bf<D_OUT, 1><<<(N_NODES * 64 + 255) / 256, 256, 0, stream>>>(
        h2, dinv, offs, ebuf, b2, out, N_NODES);
}

// Round 4
// 268.765 us; speedup vs baseline: 4.7548x; 1.1049x over previous
//
#include <hip/hip_runtime.h>
#include <hip/hip_bf16.h>
#include <math.h>

#define N_NODES 50000
#define N_EDGES 800000
#define D_IN 256
#define D_HID 256
#define D_OUT 128

typedef unsigned short ushort_t;
typedef __attribute__((ext_vector_type(8))) short bf16x8;
typedef __attribute__((ext_vector_type(4))) float f32x4;

__device__ inline float bf2f(ushort_t u) {
    union { unsigned int i; float f; } v; v.i = ((unsigned int)u) << 16; return v.f;
}
__device__ inline ushort_t f2bf(float f) {
    __hip_bfloat16 h = __float2bfloat16(f);  // RNE
    return *reinterpret_cast<ushort_t*>(&h);
}

// ================= degree =================

__global__ void k_count(const int* __restrict__ dst, int* __restrict__ degI, int e) {
    int i = blockIdx.x * 256 + threadIdx.x;
    if (i < e) atomicAdd(&degI[dst[i]], 1);
}

// ================= scan over PADDED degrees (pad to multiple of 8) =================

__global__ void k_block_sums(const int* __restrict__ degI, int* __restrict__ bsum, int n) {
    __shared__ int s[256];
    int i = blockIdx.x * 256 + threadIdx.x;
    int v = 0;
    if (i < n) v = (degI[i] + 7) & ~7;
    s[threadIdx.x] = v;
    __syncthreads();
    for (int st = 128; st > 0; st >>= 1) {
        if (threadIdx.x < st) s[threadIdx.x] += s[threadIdx.x + st];
        __syncthreads();
    }
    if (threadIdx.x == 0) bsum[blockIdx.x] = s[0];
}

__global__ void k_scan_bsums(int* __restrict__ bsum, int nb) {
    __shared__ int s[256];
    int t = threadIdx.x;
    s[t] = (t < nb) ? bsum[t] : 0;
    __syncthreads();
    for (int off = 1; off < 256; off <<= 1) {
        int v = 0;
        if (t >= off) v = s[t - off];
        __syncthreads();
        if (t >= off) s[t] += v;
        __syncthreads();
    }
    if (t < nb) bsum[t] = (t == 0) ? 0 : s[t - 1];
}

// also computes dinv = rsqrt(1+deg)
__global__ void k_scan_apply(const int* __restrict__ degI, const int* __restrict__ bsum,
                             int* __restrict__ offs, int* __restrict__ cursor,
                             float* __restrict__ dinv, int n) {
    __shared__ int s[256];
    int t = threadIdx.x;
    int i = blockIdx.x * 256 + t;
    int deg = (i < n) ? degI[i] : 0;
    int v = (deg + 7) & ~7;
    s[t] = v;
    __syncthreads();
    for (int off = 1; off < 256; off <<= 1) {
        int u = 0;
        if (t >= off) u = s[t - off];
        __syncthreads();
        if (t >= off) s[t] += u;
        __syncthreads();
    }
    int excl = s[t] - v + bsum[blockIdx.x];
    if (i < n) {
        offs[i] = excl;
        cursor[i] = excl;
        dinv[i] = rsqrtf((float)(1 + deg));
        if (i == n - 1) offs[n] = excl + v;
    }
}

__global__ void k_fill(const int* __restrict__ src, const int* __restrict__ dst,
                       int* __restrict__ cursor, int* __restrict__ ebuf, int e) {
    int i = blockIdx.x * 256 + threadIdx.x;
    if (i < e) {
        int d = dst[i];
        int pos = atomicAdd(&cursor[d], 1);
        ebuf[pos] = src[i];
    }
}

// fill padding slots with the zero-row index (N_NODES)
__global__ void k_pad(const int* __restrict__ degI, const int* __restrict__ offs,
                      int* __restrict__ ebuf, int n) {
    int i = blockIdx.x * 256 + threadIdx.x;
    if (i < n) {
        int b = offs[i] + degI[i];
        int e = offs[i + 1];
        for (int p = b; p < e; ++p) ebuf[p] = N_NODES;
    }
}

// ================= weight transpose+convert + zero-row init =================
// Wt1[n][k]=bf16(W1[k][n]) (256x256), Wt2[n][k]=bf16(W2[k][n]) (128 rows x 256)
// tail threads zero h1 row 50000 (256 elems) and h2 row 50000 (128 elems)

__global__ void k_convW(const float* __restrict__ W1, const float* __restrict__ W2,
                        ushort_t* __restrict__ Wt1, ushort_t* __restrict__ Wt2,
                        ushort_t* __restrict__ h1z, ushort_t* __restrict__ h2z) {
    int i = blockIdx.x * 256 + threadIdx.x;
    const int n1 = D_IN * D_HID;       // 65536
    const int n2 = D_HID * D_OUT;      // 32768
    if (i < n1) {
        int k = i / D_HID, n = i % D_HID;
        Wt1[(size_t)n * D_IN + k] = f2bf(W1[i]);
    } else if (i < n1 + n2) {
        int j = i - n1;
        int k = j / D_OUT, n = j % D_OUT;
        Wt2[(size_t)n * D_HID + k] = f2bf(W2[j]);
    } else {
        int j = i - n1 - n2;
        if (j < D_HID) h1z[j] = 0;
        else if (j < D_HID + D_OUT) h2z[j - D_HID] = 0;
    }
}

// ================= bf16 MFMA GEMM with dinv-scaled epilogue =================
// C[M,N](bf16) = (A[M,K] * Bt[N,K]^T) * dinv[row]; 128x128 tile, 4 waves, BK=32.

template <bool A_IS_BF16>
__global__ __launch_bounds__(256) void k_gemm_mfma(const void* __restrict__ Av,
                                                   const ushort_t* __restrict__ Bt,
                                                   const float* __restrict__ dinvD,
                                                   ushort_t* __restrict__ C,
                                                   int M, int K, int N) {
    __shared__ ushort_t As[128 * 40];
    __shared__ ushort_t Bs[128 * 40];

    const int t = threadIdx.x;
    const int lane = t & 63;
    const int w = t >> 6;
    const int wr = w >> 1, wc = w & 1;
    const int m0 = blockIdx.x * 128;
    const int n0 = blockIdx.y * 128;

    const int srow = t >> 1;
    const int scol = (t & 1) * 16;

    f32x4 acc[4][4];
#pragma unroll
    for (int m = 0; m < 4; ++m)
#pragma unroll
        for (int n = 0; n < 4; ++n)
#pragma unroll
            for (int i = 0; i < 4; ++i) acc[m][n][i] = 0.0f;

    for (int kt = 0; kt < K; kt += 32) {
        const int gr = m0 + srow;
        if (A_IS_BF16) {
            const ushort_t* A = (const ushort_t*)Av;
            uint4 v0 = make_uint4(0, 0, 0, 0), v1 = make_uint4(0, 0, 0, 0);
            if (gr < M) {
                const uint4* p = (const uint4*)(A + (size_t)gr * K + kt + scol);
                v0 = p[0]; v1 = p[1];
            }
            *(uint4*)&As[srow * 40 + scol] = v0;
            *(uint4*)&As[srow * 40 + scol + 8] = v1;
        } else {
            const float* A = (const float*)Av;
#pragma unroll
            for (int i = 0; i < 4; ++i) {
                float4 v = make_float4(0.f, 0.f, 0.f, 0.f);
                if (gr < M) v = *(const float4*)(A + (size_t)gr * K + kt + scol + 4 * i);
                ushort4 u;
                u.x = f2bf(v.x); u.y = f2bf(v.y); u.z = f2bf(v.z); u.w = f2bf(v.w);
                *(ushort4*)&As[srow * 40 + scol + 4 * i] = u;
            }
        }
        {
            const uint4* p = (const uint4*)(Bt + (size_t)(n0 + srow) * K + kt + scol);
            uint4 v0 = p[0], v1 = p[1];
            *(uint4*)&Bs[srow * 40 + scol] = v0;
            *(uint4*)&Bs[srow * 40 + scol + 8] = v1;
        }
        __syncthreads();

        const int kg = (lane >> 4) * 8;
        const int lr = lane & 15;
        bf16x8 a[4], b[4];
#pragma unroll
        for (int m = 0; m < 4; ++m)
            a[m] = *(const bf16x8*)&As[(wr * 64 + m * 16 + lr) * 40 + kg];
#pragma unroll
        for (int n = 0; n < 4; ++n)
            b[n] = *(const bf16x8*)&Bs[(wc * 64 + n * 16 + lr) * 40 + kg];
#pragma unroll
        for (int m = 0; m < 4; ++m)
#pragma unroll
            for (int n = 0; n < 4; ++n)
                acc[m][n] = __builtin_amdgcn_mfma_f32_16x16x32_bf16(a[m], b[n], acc[m][n], 0, 0, 0);
        __syncthreads();
    }

    const int lr = lane & 15;
    const int rg = (lane >> 4) * 4;
#pragma unroll
    for (int m = 0; m < 4; ++m) {
        const int rb = m0 + wr * 64 + m * 16 + rg;
#pragma unroll
        for (int i = 0; i < 4; ++i) {
            const int row = rb + i;
            if (row < M) {
                const float dr = dinvD[row];
#pragma unroll
                for (int n = 0; n < 4; ++n) {
                    const int col = n0 + wc * 64 + n * 16 + lr;
                    C[(size_t)row * N + col] = f2bf(acc[m][n][i] * dr);
                }
            }
        }
    }
}

// ================= CSR gather: pure row-sum of pre-scaled h' =================
// out[node] = F(dinv[node] * (h'[node] + sum_{e} h'[src_e]) + bias)
// Edge lists are padded to multiples of 8 with the zero row.
// MODE 0: F = relu, bf16 out. MODE 1: F = sigmoid, f32 out.

template <int DIM, int MODE>
__global__ __launch_bounds__(256) void k_gather_bf(const ushort_t* __restrict__ h,
                                                   const float* __restrict__ dinv,
                                                   const int* __restrict__ offs,
                                                   const int* __restrict__ ebuf,
                                                   const float* __restrict__ bias,
                                                   void* __restrict__ outv, int n) {
    constexpr int VEC = DIM / 64;  // 4 or 2
    const int node = (blockIdx.x * 256 + threadIdx.x) >> 6;
    const int lane = threadIdx.x & 63;
    if (node >= n) return;

    const int base = lane * VEC;
    const ushort_t* hb = h + base;
    const float di = dinv[node];

    float acc[VEC];
    if (VEC == 4) {
        ushort4 u = *(const ushort4*)(hb + (size_t)node * DIM);
        acc[0] = bf2f(u.x); acc[1] = bf2f(u.y); acc[2] = bf2f(u.z); acc[3] = bf2f(u.w);
    } else {
        ushort2 u = *(const ushort2*)(hb + (size_t)node * DIM);
        acc[0] = bf2f(u.x); acc[1] = bf2f(u.y);
    }

    int e = offs[node];
    const int e1 = offs[node + 1];
    for (; e < e1; e += 8) {
        int s[8];
#pragma unroll
        for (int j = 0; j < 8; ++j) s[j] = ebuf[e + j];
        if (VEC == 4) {
            ushort4 u[8];
#pragma unroll
            for (int j = 0; j < 8; ++j) u[j] = *(const ushort4*)(hb + (size_t)s[j] * DIM);
#pragma unroll
            for (int j = 0; j < 8; ++j) {
                acc[0] += bf2f(u[j].x); acc[1] += bf2f(u[j].y);
                acc[2] += bf2f(u[j].z); acc[3] += bf2f(u[j].w);
            }
        } else {
            ushort2 u[8];
#pragma unroll
            for (int j = 0; j < 8; ++j) u[j] = *(const ushort2*)(hb + (size_t)s[j] * DIM);
#pragma unroll
            for (int j = 0; j < 8; ++j) {
                acc[0] += bf2f(u[j].x); acc[1] += bf2f(u[j].y);
            }
        }
    }

    if (MODE == 0) {
        ushort_t* out = (ushort_t*)outv;
        if (VEC == 4) {
            ushort4 u;
            u.x = f2bf(fmaxf(di * acc[0] + bias[base + 0], 0.f));
            u.y = f2bf(fmaxf(di * acc[1] + bias[base + 1], 0.f));
            u.z = f2bf(fmaxf(di * acc[2] + bias[base + 2], 0.f));
            u.w = f2bf(fmaxf(di * acc[3] + bias[base + 3], 0.f));
            *(ushort4*)(out + (size_t)node * DIM + base) = u;
        } else {
            ushort2 u;
            u.x = f2bf(fmaxf(di * acc[0] + bias[base + 0], 0.f));
            u.y = f2bf(fmaxf(di * acc[1] + bias[base + 1], 0.f));
            *(ushort2*)(out + (size_t)node * DIM + base) = u;
        }
    } else {
        float* out = (float*)outv;
        if (VEC == 2) {
            const float v0 = di * acc[0] + bias[base + 0];
            const float v1 = di * acc[1] + bias[base + 1];
            float2 r;
            r.x = 1.0f / (1.0f + expf(-v0));
            r.y = 1.0f / (1.0f + expf(-v1));
            *(float2*)(out + (size_t)node * DIM + base) = r;
        } else {
#pragma unroll
            for (int j = 0; j < VEC; ++j) {
                const float v = di * acc[j] + bias[base + j];
                out[(size_t)node * DIM + base + j] = 1.0f / (1.0f + expf(-v));
            }
        }
    }
}

// ================= launch =================

extern "C" void kernel_launch(void* const* d_in, const int* in_sizes, int n_in,
                              void* d_out, int out_size, void* d_ws, size_t ws_size,
                              hipStream_t stream) {
    const float* x  = (const float*)d_in[0];
    const int*   ei = (const int*)d_in[1];
    const float* W1 = (const float*)d_in[2];
    const float* b1 = (const float*)d_in[3];
    const float* W2 = (const float*)d_in[4];
    const float* b2 = (const float*)d_in[5];
    float* out = (float*)d_out;

    float* wsf    = (float*)d_ws;
    float* dinv   = wsf;                            // [50048] f32
    int*   degI   = (int*)(wsf + 50048);            // [50048]
    int*   offs   = degI + 50048;                   // [50064] (uses 50001)
    int*   cursor = offs + 50064;                   // [50048]
    int*   bsum   = cursor + 50048;                 // [256]
    int*   ebuf   = bsum + 256;                     // [1200128] padded CSR
    ushort_t* Wt1 = (ushort_t*)(ebuf + 1200128);    // [65536] bf16
    ushort_t* Wt2 = Wt1 + 65536;                    // [32768] bf16
    ushort_t* h1  = Wt2 + 32768;                    // [(50048)*256] bf16, row 50000 = zeros
    ushort_t* agg1= h1 + (size_t)50048 * D_HID;     // [50048*256] bf16
    ushort_t* h2  = agg1 + (size_t)50048 * D_HID;   // [50048*128] bf16, row 50000 = zeros

    const int* src = ei;
    const int* dst = ei + N_EDGES;

    const int blocksN = (N_NODES + 255) / 256;  // 196
    const int blocksE = (N_EDGES + 255) / 256;

    // ---- CSR build (padded) + norms ----
    hipMemsetAsync(degI, 0, N_NODES * sizeof(int), stream);
    k_count<<<blocksE, 256, 0, stream>>>(dst, degI, N_EDGES);
    k_block_sums<<<blocksN, 256, 0, stream>>>(degI, bsum, N_NODES);
    k_scan_bsums<<<1, 256, 0, stream>>>(bsum, blocksN);
    k_scan_apply<<<blocksN, 256, 0, stream>>>(degI, bsum, offs, cursor, dinv, N_NODES);
    k_fill<<<blocksE, 256, 0, stream>>>(src, dst, cursor, ebuf, N_EDGES);
    k_pad<<<blocksN, 256, 0, stream>>>(degI, offs, ebuf, N_NODES);

    // ---- weights + zero rows ----
    {
        const int tot = D_IN * D_HID + D_HID * D_OUT + D_HID + D_OUT;
        k_convW<<<(tot + 255) / 256, 256, 0, stream>>>(W1, W2, Wt1, Wt2,
                                                       h1 + (size_t)N_NODES * D_HID,
                                                       h2 + (size_t)N_NODES * D_OUT);
    }

    // ---- layer 1 GEMM: h1 = bf16((x @ W1) * dinv[row]) ----
    {
        dim3 g((N_NODES + 127) / 128, D_HID / 128);
        k_gemm_mfma<false><<<g, 256, 0, stream>>>(x, Wt1, dinv, h1, N_NODES, D_IN, D_HID);
    }

    // ---- aggregate 256-dim: agg1 = bf16(relu(dinv*(sum) + b1)) ----
    k_gather_bf<D_HID, 0><<<(N_NODES * 64 + 255) / 256, 256, 0, stream>>>(
        h1, dinv, offs, ebuf, b1, agg1, N_NODES);

    // ---- layer 2 GEMM: h2 = bf16((agg1 @ W2) * dinv[row]) ----
    {
        dim3 g((N_NODES + 127) / 128, D_OUT / 128);
        k_gemm_mfma<true><<<g, 256, 0, stream>>>(agg1, Wt2, dinv, h2, N_NODES, D_HID, D_OUT);
    }

    // ---- aggregate 128-dim: out = sigmoid(dinv*(sum) + b2) ----
    k_gather_bf<D_OUT, 1><<<(N_NODES * 64 + 255) / 256, 256, 0, stream>>>(
        h2, dinv, offs, ebuf, b2, out, N_NODES);
}

// Round 5
// 261.158 us; speedup vs baseline: 4.8933x; 1.0291x over previous
//
#include <hip/hip_runtime.h>
#include <hip/hip_bf16.h>
#include <math.h>

#define N_NODES 50000
#define N_EDGES 800000
#define D_IN 256
#define D_HID 256
#define D_OUT 128

typedef unsigned short ushort_t;
typedef __attribute__((ext_vector_type(8))) short bf16x8;
typedef __attribute__((ext_vector_type(4))) float f32x4;

__device__ inline float bf2f(ushort_t u) {
    union { unsigned int i; float f; } v; v.i = ((unsigned int)u) << 16; return v.f;
}
__device__ inline ushort_t f2bf(float f) {
    __hip_bfloat16 h = __float2bfloat16(f);  // RNE
    return *reinterpret_cast<ushort_t*>(&h);
}
// bf16 pair unpack: lo = bits<<16, hi = bits&0xffff0000 (1 VALU op each)
__device__ inline float blo(unsigned u) {
    union { unsigned i; float f; } v; v.i = u << 16; return v.f;
}
__device__ inline float bhi(unsigned u) {
    union { unsigned i; float f; } v; v.i = u & 0xffff0000u; return v.f;
}

// ================= degree =================

__global__ void k_count(const int* __restrict__ dst, int* __restrict__ degI, int e) {
    int i = blockIdx.x * 256 + threadIdx.x;
    if (i < e) atomicAdd(&degI[dst[i]], 1);
}

// ================= scan over PADDED degrees (pad to multiple of 16) =================

__global__ void k_block_sums(const int* __restrict__ degI, int* __restrict__ bsum, int n) {
    __shared__ int s[256];
    int i = blockIdx.x * 256 + threadIdx.x;
    int v = 0;
    if (i < n) v = (degI[i] + 15) & ~15;
    s[threadIdx.x] = v;
    __syncthreads();
    for (int st = 128; st > 0; st >>= 1) {
        if (threadIdx.x < st) s[threadIdx.x] += s[threadIdx.x + st];
        __syncthreads();
    }
    if (threadIdx.x == 0) bsum[blockIdx.x] = s[0];
}

__global__ void k_scan_bsums(int* __restrict__ bsum, int nb) {
    __shared__ int s[256];
    int t = threadIdx.x;
    s[t] = (t < nb) ? bsum[t] : 0;
    __syncthreads();
    for (int off = 1; off < 256; off <<= 1) {
        int v = 0;
        if (t >= off) v = s[t - off];
        __syncthreads();
        if (t >= off) s[t] += v;
        __syncthreads();
    }
    if (t < nb) bsum[t] = (t == 0) ? 0 : s[t - 1];
}

// computes offs/cursor/dinv AND fills padding slots with zero-row index
__global__ void k_scan_apply(const int* __restrict__ degI, const int* __restrict__ bsum,
                             int* __restrict__ offs, int* __restrict__ cursor,
                             float* __restrict__ dinv, int* __restrict__ ebuf, int n) {
    __shared__ int s[256];
    int t = threadIdx.x;
    int i = blockIdx.x * 256 + t;
    int deg = (i < n) ? degI[i] : 0;
    int v = (deg + 15) & ~15;
    s[t] = v;
    __syncthreads();
    for (int off = 1; off < 256; off <<= 1) {
        int u = 0;
        if (t >= off) u = s[t - off];
        __syncthreads();
        if (t >= off) s[t] += u;
        __syncthreads();
    }
    int excl = s[t] - v + bsum[blockIdx.x];
    if (i < n) {
        offs[i] = excl;
        cursor[i] = excl;
        dinv[i] = rsqrtf((float)(1 + deg));
        for (int p = excl + deg; p < excl + v; ++p) ebuf[p] = N_NODES;
        if (i == n - 1) offs[n] = excl + v;
    }
}

__global__ void k_fill(const int* __restrict__ src, const int* __restrict__ dst,
                       int* __restrict__ cursor, int* __restrict__ ebuf, int e) {
    int i = blockIdx.x * 256 + threadIdx.x;
    if (i < e) {
        int d = dst[i];
        int pos = atomicAdd(&cursor[d], 1);
        ebuf[pos] = src[i];
    }
}

// ================= weight transpose+convert + zero-row init =================

__global__ void k_convW(const float* __restrict__ W1, const float* __restrict__ W2,
                        ushort_t* __restrict__ Wt1, ushort_t* __restrict__ Wt2,
                        ushort_t* __restrict__ h1z, ushort_t* __restrict__ h2z) {
    int i = blockIdx.x * 256 + threadIdx.x;
    const int n1 = D_IN * D_HID;       // 65536
    const int n2 = D_HID * D_OUT;      // 32768
    if (i < n1) {
        int k = i / D_HID, n = i % D_HID;
        Wt1[(size_t)n * D_IN + k] = f2bf(W1[i]);
    } else if (i < n1 + n2) {
        int j = i - n1;
        int k = j / D_OUT, n = j % D_OUT;
        Wt2[(size_t)n * D_HID + k] = f2bf(W2[j]);
    } else {
        int j = i - n1 - n2;
        if (j < D_HID) h1z[j] = 0;
        else if (j < D_HID + D_OUT) h2z[j - D_HID] = 0;
    }
}

// ================= bf16 MFMA GEMM with dinv-scaled epilogue =================
// C[M,N](bf16) = (A[M,K] * Bt[N,K]^T) * dinv[row]; 128x128 tile, 4 waves, BK=32.

template <bool A_IS_BF16>
__global__ __launch_bounds__(256) void k_gemm_mfma(const void* __restrict__ Av,
                                                   const ushort_t* __restrict__ Bt,
                                                   const float* __restrict__ dinvD,
                                                   ushort_t* __restrict__ C,
                                                   int M, int K, int N) {
    __shared__ ushort_t As[128 * 40];
    __shared__ ushort_t Bs[128 * 40];

    const int t = threadIdx.x;
    const int lane = t & 63;
    const int w = t >> 6;
    const int wr = w >> 1, wc = w & 1;
    const int m0 = blockIdx.x * 128;
    const int n0 = blockIdx.y * 128;

    const int srow = t >> 1;
    const int scol = (t & 1) * 16;

    f32x4 acc[4][4];
#pragma unroll
    for (int m = 0; m < 4; ++m)
#pragma unroll
        for (int n = 0; n < 4; ++n)
#pragma unroll
            for (int i = 0; i < 4; ++i) acc[m][n][i] = 0.0f;

    for (int kt = 0; kt < K; kt += 32) {
        const int gr = m0 + srow;
        if (A_IS_BF16) {
            const ushort_t* A = (const ushort_t*)Av;
            uint4 v0 = make_uint4(0, 0, 0, 0), v1 = make_uint4(0, 0, 0, 0);
            if (gr < M) {
                const uint4* p = (const uint4*)(A + (size_t)gr * K + kt + scol);
                v0 = p[0]; v1 = p[1];
            }
            *(uint4*)&As[srow * 40 + scol] = v0;
            *(uint4*)&As[srow * 40 + scol + 8] = v1;
        } else {
            const float* A = (const float*)Av;
#pragma unroll
            for (int i = 0; i < 4; ++i) {
                float4 v = make_float4(0.f, 0.f, 0.f, 0.f);
                if (gr < M) v = *(const float4*)(A + (size_t)gr * K + kt + scol + 4 * i);
                ushort4 u;
                u.x = f2bf(v.x); u.y = f2bf(v.y); u.z = f2bf(v.z); u.w = f2bf(v.w);
                *(ushort4*)&As[srow * 40 + scol + 4 * i] = u;
            }
        }
        {
            const uint4* p = (const uint4*)(Bt + (size_t)(n0 + srow) * K + kt + scol);
            uint4 v0 = p[0], v1 = p[1];
            *(uint4*)&Bs[srow * 40 + scol] = v0;
            *(uint4*)&Bs[srow * 40 + scol + 8] = v1;
        }
        __syncthreads();

        const int kg = (lane >> 4) * 8;
        const int lr = lane & 15;
        bf16x8 a[4], b[4];
#pragma unroll
        for (int m = 0; m < 4; ++m)
            a[m] = *(const bf16x8*)&As[(wr * 64 + m * 16 + lr) * 40 + kg];
#pragma unroll
        for (int n = 0; n < 4; ++n)
            b[n] = *(const bf16x8*)&Bs[(wc * 64 + n * 16 + lr) * 40 + kg];
#pragma unroll
        for (int m = 0; m < 4; ++m)
#pragma unroll
            for (int n = 0; n < 4; ++n)
                acc[m][n] = __builtin_amdgcn_mfma_f32_16x16x32_bf16(a[m], b[n], acc[m][n], 0, 0, 0);
        __syncthreads();
    }

    const int lr = lane & 15;
    const int rg = (lane >> 4) * 4;
#pragma unroll
    for (int m = 0; m < 4; ++m) {
        const int rb = m0 + wr * 64 + m * 16 + rg;
#pragma unroll
        for (int i = 0; i < 4; ++i) {
            const int row = rb + i;
            if (row < M) {
                const float dr = dinvD[row];
#pragma unroll
                for (int n = 0; n < 4; ++n) {
                    const int col = n0 + wc * 64 + n * 16 + lr;
                    C[(size_t)row * N + col] = f2bf(acc[m][n][i] * dr);
                }
            }
        }
    }
}

// ================= pipelined CSR gather =================
// out[node] = F(dinv[node] * (h'[node] + sum_e h'[src_e]) + bias)
// Edge lists padded to multiples of 16 with the zero row.
// 16-edge batches: 16 row loads in flight; next batch's indices prefetched
// during current batch's row latency. Indices scalarized (wave-uniform).
// MODE 0: F = relu, bf16 out. MODE 1: F = sigmoid, f32 out.

__device__ inline void ld_idx16(const int* __restrict__ p, int* s) {
    int4 a = ((const int4*)p)[0];
    int4 b = ((const int4*)p)[1];
    int4 c = ((const int4*)p)[2];
    int4 d = ((const int4*)p)[3];
    s[0]  = __builtin_amdgcn_readfirstlane(a.x);
    s[1]  = __builtin_amdgcn_readfirstlane(a.y);
    s[2]  = __builtin_amdgcn_readfirstlane(a.z);
    s[3]  = __builtin_amdgcn_readfirstlane(a.w);
    s[4]  = __builtin_amdgcn_readfirstlane(b.x);
    s[5]  = __builtin_amdgcn_readfirstlane(b.y);
    s[6]  = __builtin_amdgcn_readfirstlane(b.z);
    s[7]  = __builtin_amdgcn_readfirstlane(b.w);
    s[8]  = __builtin_amdgcn_readfirstlane(c.x);
    s[9]  = __builtin_amdgcn_readfirstlane(c.y);
    s[10] = __builtin_amdgcn_readfirstlane(c.z);
    s[11] = __builtin_amdgcn_readfirstlane(c.w);
    s[12] = __builtin_amdgcn_readfirstlane(d.x);
    s[13] = __builtin_amdgcn_readfirstlane(d.y);
    s[14] = __builtin_amdgcn_readfirstlane(d.z);
    s[15] = __builtin_amdgcn_readfirstlane(d.w);
}

template <int DIM, int MODE>
__global__ __launch_bounds__(256) void k_gather_bf(const ushort_t* __restrict__ h,
                                                   const float* __restrict__ dinv,
                                                   const int* __restrict__ offs,
                                                   const int* __restrict__ ebuf,
                                                   const float* __restrict__ bias,
                                                   void* __restrict__ outv, int n) {
    constexpr int VEC = DIM / 64;  // 4 or 2
    const int node = (blockIdx.x * 256 + threadIdx.x) >> 6;
    const int lane = threadIdx.x & 63;
    if (node >= n) return;

    const int base = lane * VEC;
    const ushort_t* hb = h + base;
    const float di = dinv[node];

    float acc[VEC];
    if (VEC == 4) {
        uint2 u = *(const uint2*)(hb + (size_t)node * DIM);
        acc[0] = blo(u.x); acc[1] = bhi(u.x); acc[2] = blo(u.y); acc[3] = bhi(u.y);
    } else {
        unsigned u = *(const unsigned*)(hb + (size_t)node * DIM);
        acc[0] = blo(u); acc[1] = bhi(u);
    }

    int e = __builtin_amdgcn_readfirstlane(offs[node]);
    const int e1 = __builtin_amdgcn_readfirstlane(offs[node + 1]);

    int cs[16], ns[16];
    bool have = e < e1;
    if (have) ld_idx16(ebuf + e, cs);

    while (have) {
        const int en = e + 16;
        const bool hn = en < e1;
        if (VEC == 4) {
            uint2 u[16];
#pragma unroll
            for (int j = 0; j < 16; ++j)
                u[j] = *(const uint2*)(hb + (size_t)cs[j] * DIM);
            if (hn) ld_idx16(ebuf + en, ns);
#pragma unroll
            for (int j = 0; j < 16; ++j) {
                acc[0] += blo(u[j].x); acc[1] += bhi(u[j].x);
                acc[2] += blo(u[j].y); acc[3] += bhi(u[j].y);
            }
        } else {
            unsigned u[16];
#pragma unroll
            for (int j = 0; j < 16; ++j)
                u[j] = *(const unsigned*)(hb + (size_t)cs[j] * DIM);
            if (hn) ld_idx16(ebuf + en, ns);
#pragma unroll
            for (int j = 0; j < 16; ++j) {
                acc[0] += blo(u[j]); acc[1] += bhi(u[j]);
            }
        }
        e = en; have = hn;
#pragma unroll
        for (int j = 0; j < 16; ++j) cs[j] = ns[j];
    }

    if (MODE == 0) {
        ushort_t* out = (ushort_t*)outv;
        if (VEC == 4) {
            ushort4 u;
            u.x = f2bf(fmaxf(di * acc[0] + bias[base + 0], 0.f));
            u.y = f2bf(fmaxf(di * acc[1] + bias[base + 1], 0.f));
            u.z = f2bf(fmaxf(di * acc[2] + bias[base + 2], 0.f));
            u.w = f2bf(fmaxf(di * acc[3] + bias[base + 3], 0.f));
            *(ushort4*)(out + (size_t)node * DIM + base) = u;
        } else {
            ushort2 u;
            u.x = f2bf(fmaxf(di * acc[0] + bias[base + 0], 0.f));
            u.y = f2bf(fmaxf(di * acc[1] + bias[base + 1], 0.f));
            *(ushort2*)(out + (size_t)node * DIM + base) = u;
        }
    } else {
        float* out = (float*)outv;
        const float v0 = di * acc[0] + bias[base + 0];
        const float v1 = di * acc[1] + bias[base + 1];
        float2 r;
        r.x = 1.0f / (1.0f + expf(-v0));
        r.y = 1.0f / (1.0f + expf(-v1));
        *(float2*)(out + (size_t)node * DIM + base) = r;
    }
}

// ================= launch =================

extern "C" void kernel_launch(void* const* d_in, const int* in_sizes, int n_in,
                              void* d_out, int out_size, void* d_ws, size_t ws_size,
                              hipStream_t stream) {
    const float* x  = (const float*)d_in[0];
    const int*   ei = (const int*)d_in[1];
    const float* W1 = (const float*)d_in[2];
    const float* b1 = (const float*)d_in[3];
    const float* W2 = (const float*)d_in[4];
    const float* b2 = (const float*)d_in[5];
    float* out = (float*)d_out;

    float* wsf    = (float*)d_ws;
    float* dinv   = wsf;                            // [50048] f32
    int*   degI   = (int*)(wsf + 50048);            // [50048]
    int*   offs   = degI + 50048;                   // [50064] (uses 50001)
    int*   cursor = offs + 50064;                   // [50048]
    int*   bsum   = cursor + 50048;                 // [256]
    int*   ebuf   = bsum + 256;                     // [1600000] padded CSR (<=1.55M used)
    ushort_t* Wt1 = (ushort_t*)(ebuf + 1600000);    // [65536] bf16
    ushort_t* Wt2 = Wt1 + 65536;                    // [32768] bf16
    ushort_t* h1  = Wt2 + 32768;                    // [50048*256] bf16, row 50000 = zeros
    ushort_t* agg1= h1 + (size_t)50048 * D_HID;     // [50048*256] bf16
    ushort_t* h2  = agg1 + (size_t)50048 * D_HID;   // [50048*128] bf16, row 50000 = zeros

    const int* src = ei;
    const int* dst = ei + N_EDGES;

    const int blocksN = (N_NODES + 255) / 256;  // 196
    const int blocksE = (N_EDGES + 255) / 256;

    // ---- CSR build (padded to 16) + norms ----
    hipMemsetAsync(degI, 0, N_NODES * sizeof(int), stream);
    k_count<<<blocksE, 256, 0, stream>>>(dst, degI, N_EDGES);
    k_block_sums<<<blocksN, 256, 0, stream>>>(degI, bsum, N_NODES);
    k_scan_bsums<<<1, 256, 0, stream>>>(bsum, blocksN);
    k_scan_apply<<<blocksN, 256, 0, stream>>>(degI, bsum, offs, cursor, dinv, ebuf, N_NODES);
    k_fill<<<blocksE, 256, 0, stream>>>(src, dst, cursor, ebuf, N_EDGES);

    // ---- weights + zero rows ----
    {
        const int tot = D_IN * D_HID + D_HID * D_OUT + D_HID + D_OUT;
        k_convW<<<(tot + 255) / 256, 256, 0, stream>>>(W1, W2, Wt1, Wt2,
                                                       h1 + (size_t)N_NODES * D_HID,
                                                       h2 + (size_t)N_NODES * D_OUT);
    }

    // ---- layer 1 GEMM: h1 = bf16((x @ W1) * dinv[row]) ----
    {
        dim3 g((N_NODES + 127) / 128, D_HID / 128);
        k_gemm_mfma<false><<<g, 256, 0, stream>>>(x, Wt1, dinv, h1, N_NODES, D_IN, D_HID);
    }

    // ---- aggregate 256-dim: agg1 = bf16(relu(dinv*(sum) + b1)) ----
    k_gather_bf<D_HID, 0><<<(N_NODES * 64 + 255) / 256, 256, 0, stream>>>(
        h1, dinv, offs, ebuf, b1, agg1, N_NODES);

    // ---- layer 2 GEMM: h2 = bf16((agg1 @ W2) * dinv[row]) ----
    {
        dim3 g((N_NODES + 127) / 128, D_OUT / 128);
        k_gemm_mfma<true><<<g, 256, 0, stream>>>(agg1, Wt2, dinv, h2, N_NODES, D_HID, D_OUT);
    }

    // ---- aggregate 128-dim: out = sigmoid(dinv*(sum) + b2) ----
    k_gather_bf<D_OUT, 1><<<(N_NODES * 64 + 255) / 256, 256, 0, stream>>>(
        h2, dinv, offs, ebuf, b2, out, N_NODES);
}